// Round 19
// baseline (160.034 us; speedup 1.0000x reference)
//
#include <hip/hip_runtime.h>
#include <hip/hip_bf16.h>
#include <math.h>

typedef __attribute__((ext_vector_type(4))) float f32x4;
typedef __attribute__((ext_vector_type(16))) float f32x16;
typedef __attribute__((ext_vector_type(8))) short bf16x8;
typedef __attribute__((ext_vector_type(4))) short s16x4;
typedef __attribute__((ext_vector_type(4))) unsigned int u32x4;
typedef __attribute__((ext_vector_type(2))) unsigned int u32x2;
typedef short s16;
typedef unsigned int u32;
typedef unsigned short u16;

#define S_LEN 2048
#define HIDN  2048
#define QKVW  3072
#define NH    32
#define NKVH  8
#define HD    64

__device__ __forceinline__ s16 f2bf(float f) {
  unsigned int u = __float_as_uint(f);
  unsigned int lsb = (u >> 16) & 1u;
  u += 0x7fffu + lsb;
  return (s16)(u >> 16);
}

__device__ __forceinline__ u32 cvtpk(float lo, float hi) {
  u32 r;
  asm("v_cvt_pk_bf16_f32 %0, %1, %2" : "=v"(r) : "v"(lo), "v"(hi));
  return r;
}

__device__ __forceinline__ void gload16(const void* g, void* l) {
  __builtin_amdgcn_global_load_lds(
      (const __attribute__((address_space(1))) void*)g,
      (__attribute__((address_space(3))) void*)l, 16, 0, 0);
}

// v_permlane32_swap_b32: a.hi-lanes <-> b.lo-lanes
__device__ __forceinline__ void pls(u32& a, u32& b) {
  asm volatile("v_permlane32_swap_b32 %0, %1" : "+v"(a), "+v"(b));
}

__device__ __forceinline__ int swz7(int row) { return (row ^ (row >> 3)) & 7; }

// all 5 f32->bf16 conversions in one launch; dest regions are contiguous in ws
__global__ __launch_bounds__(256) void cvt_all(const float* __restrict__ h,
                                               const float* __restrict__ wq,
                                               const float* __restrict__ wk,
                                               const float* __restrict__ wv,
                                               const float* __restrict__ wo,
                                               s16x4* __restrict__ dst) {
  int i = blockIdx.x * 256 + threadIdx.x;
  const float* src; int off;
  if (i < 1048576)      { src = h;  off = i; }
  else if (i < 2097152) { src = wq; off = i - 1048576; }
  else if (i < 2359296) { src = wk; off = i - 2097152; }
  else if (i < 2621440) { src = wv; off = i - 2359296; }
  else                  { src = wo; off = i - 2621440; }
  if (i < 3670016) {
    float4 f = reinterpret_cast<const float4*>(src)[off];
    s16x4 o;
    o.x = f2bf(f.x); o.y = f2bf(f.y); o.z = f2bf(f.z); o.w = f2bf(f.w);
    dst[i] = o;
  }
}

__device__ __forceinline__ void storeC(s16* C, size_t idx, float v)   { C[idx] = f2bf(v); }
__device__ __forceinline__ void storeC(float* C, size_t idx, float v) { C[idx] = v; }

// C[M,N] = A[M,K] * B[N,K]^T. BM=BN=128, BK=64, 512 threads (8 waves 2x4),
// double-buffered LDS, 2-phase schedule, swz7 slot swizzle, XCD block swizzle.
template <typename OUT_T>
__global__ __launch_bounds__(512) void gemm_bt(const s16* __restrict__ A,
                                               const s16* __restrict__ B,
                                               OUT_T* __restrict__ C,
                                               int M, int N, int K, int gridX) {
  __shared__ alignas(16) s16 As[2][8192];   // [128][64], 16KB each
  __shared__ alignas(16) s16 Bs[2][8192];

  // bijective XCD swizzle (m204): each XCD gets a contiguous tile range
  const int nwg  = (M >> 7) * gridX;
  const int flat = blockIdx.x;
  const int q8   = nwg >> 3;
  const int swz  = (flat & 7) * q8 + (flat >> 3);
  const int bm   = (swz / gridX) * 128;
  const int bn   = (swz % gridX) * 128;

  const int t    = threadIdx.x;
  const int lane = t & 63;
  const int w    = t >> 6;            // 0..7
  const int wr   = (w >> 2) * 64;     // wave-tile 64x32
  const int wc   = (w & 3) * 32;
  const int lr   = lane & 15;
  const int lg   = lane >> 4;

  // staging: 16 chunks of 1KB per matrix; wave w does chunks {2w, 2w+1}
  const int srow0 = (w * 2) * 8 + (lane >> 3);
  const int srow1 = (w * 2 + 1) * 8 + (lane >> 3);
  const int sl0   = ((lane & 7) ^ swz7(srow0)) * 8;
  const int sl1   = ((lane & 7) ^ swz7(srow1)) * 8;

  f32x4 acc[4][2];
#pragma unroll
  for (int m = 0; m < 4; ++m)
#pragma unroll
    for (int n = 0; n < 2; ++n)
      acc[m][n] = (f32x4){0.f, 0.f, 0.f, 0.f};

  const int nK = K >> 6;
  int buf = 0;

  // prologue: stage tile 0
  {
    gload16(&A[(size_t)(bm + srow0) * K + sl0], (char*)As[0] + (w * 2) * 1024);
    gload16(&A[(size_t)(bm + srow1) * K + sl1], (char*)As[0] + (w * 2 + 1) * 1024);
    gload16(&B[(size_t)(bn + srow0) * K + sl0], (char*)Bs[0] + (w * 2) * 1024);
    gload16(&B[(size_t)(bn + srow1) * K + sl1], (char*)Bs[0] + (w * 2 + 1) * 1024);
  }
  __syncthreads();

  for (int ki = 0; ki < nK; ++ki) {
    if (ki + 1 < nK) {
      const int kt = (ki + 1) << 6;
      gload16(&A[(size_t)(bm + srow0) * K + kt + sl0], (char*)As[buf ^ 1] + (w * 2) * 1024);
      gload16(&A[(size_t)(bm + srow1) * K + kt + sl1], (char*)As[buf ^ 1] + (w * 2 + 1) * 1024);
      gload16(&B[(size_t)(bn + srow0) * K + kt + sl0], (char*)Bs[buf ^ 1] + (w * 2) * 1024);
      gload16(&B[(size_t)(bn + srow1) * K + kt + sl1], (char*)Bs[buf ^ 1] + (w * 2 + 1) * 1024);
    }

    bf16x8 af[4][2], bfr[2][2];
#pragma unroll
    for (int kk = 0; kk < 2; ++kk) {
#pragma unroll
      for (int m = 0; m < 4; ++m) {
        int row = wr + m * 16 + lr;
        af[m][kk] = *(bf16x8*)((char*)As[buf] + row * 128 + (((kk * 4 + lg) ^ swz7(row)) << 4));
      }
#pragma unroll
      for (int n = 0; n < 2; ++n) {
        int row = wc + n * 16 + lr;
        bfr[n][kk] = *(bf16x8*)((char*)Bs[buf] + row * 128 + (((kk * 4 + lg) ^ swz7(row)) << 4));
      }
    }

    __builtin_amdgcn_s_setprio(1);
#pragma unroll
    for (int m = 0; m < 4; ++m)
#pragma unroll
      for (int n = 0; n < 2; ++n)
#pragma unroll
        for (int kk = 0; kk < 2; ++kk)
          acc[m][n] = __builtin_amdgcn_mfma_f32_16x16x32_bf16(af[m][kk], bfr[n][kk], acc[m][n], 0, 0, 0);
    __builtin_amdgcn_s_setprio(0);

    __syncthreads();
    buf ^= 1;
  }

#pragma unroll
  for (int m = 0; m < 4; ++m)
#pragma unroll
    for (int n = 0; n < 2; ++n) {
      int row = bm + wr + m * 16 + lg * 4;
      int col = bn + wc + n * 16 + lr;
#pragma unroll
      for (int j = 0; j < 4; ++j)
        storeC(C, (size_t)(row + j) * N + col, acc[m][n][j]);
    }
}

// ---------------- flash attention: 3-way split-KV, 12-wave blocks ------------
// Block = (hk, p): phase 0 runs q-tile 63-p, phase 1 runs q-tile p (uniform
// 11-12 rounds/block). 768 threads = 3 KV-split groups x 4 heads; group g owns
// KV tiles 3i+g with private double-buffered K/V LDS (3x2x16KB = 96KB);
// 3-way in-LDS merge per phase (stride-33 pools, conflict-free).
// amdgpu_waves_per_eu(3,3): hard-clamp occupancy target -> VGPR budget 170
// (engine needs ~116; launch_bounds(768,3) alone left the heuristic at 6/EU=84).
__global__ __launch_bounds__(768)
__attribute__((amdgpu_waves_per_eu(3, 3)))
void attn_kernel(
    const s16* __restrict__ QKV,   // [2048][3072]
    const int* __restrict__ am,    // [2048]
    s16* __restrict__ Ob) {        // [2048][2048]
  // group g staging at +g*32768 (dbuf 2x16KB: K 8KB + V^T 8KB per buf)
  __shared__ alignas(16) char smem[98304];
  __shared__ float2 mlb[2][4][64];

  const int t    = threadIdx.x;
  const int g    = t >> 8;        // kv-split group 0..2
  const int tg   = t & 255;       // tid within group
  const int lane = t & 63;
  const int w    = tg >> 6;       // head index within group
  const int col  = lane & 31;     // q column (this wave's q-row index)
  const int hi   = lane >> 5;

  const int hk = blockIdx.x;
  const int p  = blockIdx.y;      // 0..31
  const int h  = hk * 4 + w;
  const int kbase = 2048 + hk * 64;
  const int vbase = 2560 + hk * 64;
  const float CF = 0.18033688f;  // 0.125 * log2(e)

  const int krow   = lane >> 3;
  const int kslotb = lane & 7;
  const int vkv    = 2 * (tg >> 3);
  const int vd8    = (tg & 7) * 8;

  char* gbase = smem + g * 32768;

  for (int phase = 0; phase < 2; ++phase) {
    const int qt = phase ? p : 63 - p;
    const int nt = (qt >> 1) + 1;
    const int R  = (nt + 2) / 3;    // rounds (3 tiles per round across groups)
    const int qrow = qt * 32 + col;

    bf16x8 qf[4];
#pragma unroll
    for (int ds = 0; ds < 4; ++ds)
      qf[ds] = *(const bf16x8*)&QKV[(size_t)qrow * QKVW + h * 64 + ds * 16 + hi * 8];

    // ---- prologue: group g stages tile g into its buf 0 ----
    if (g < nt) {
      char* Kn = gbase;
      char* Vn = Kn + 8192;
#pragma unroll
      for (int pp = 0; pp < 2; ++pp) {
        int c   = w * 2 + pp;
        int row = c * 8 + krow;
        int slot = kslotb ^ swz7(row);
        gload16(&QKV[(size_t)(g * 64 + row) * QKVW + kbase + slot * 8], Kn + c * 1024);
      }
      bf16x8 va = *(const bf16x8*)&QKV[(size_t)(g * 64 + vkv) * QKVW + vbase + vd8];
      bf16x8 vb = *(const bf16x8*)&QKV[(size_t)(g * 64 + vkv + 1) * QKVW + vbase + vd8];
#pragma unroll
      for (int i = 0; i < 8; ++i) {
        int d = vd8 + i;
        u32 pk = (u32)(u16)va[i] | ((u32)(u16)vb[i] << 16);
        *(u32*)&Vn[(d * 128 + vkv * 2) ^ (swz7(d) << 4)] = pk;
      }
    }
    int acur = am[g * 64 + lane];

    float m_i = -1e30f, l_part = 0.f;
    f32x16 Oacc[2];
#pragma unroll
    for (int b = 0; b < 2; ++b)
#pragma unroll
      for (int i = 0; i < 16; ++i) Oacc[b][i] = 0.f;
    __syncthreads();

    for (int it = 0; it < R; ++it) {
      const int buf  = it & 1;
      const int tile = 3 * it + g;
      const bool valid = (tile < nt);
      const int kv0  = tile * 64;
      const bool pre = (tile + 3 < nt);

      char* Kc = gbase + buf * 16384;
      char* Vc = Kc + 8192;
      char* Kn = gbase + (buf ^ 1) * 16384;
      char* Vn = Kn + 8192;

      // ---- async stage of this group's next tile (issue early) ----
      bf16x8 va, vb;
      int anext = 0;
      if (pre) {
        const int nk0 = kv0 + 192;
#pragma unroll
        for (int pp = 0; pp < 2; ++pp) {
          int c   = w * 2 + pp;
          int row = c * 8 + krow;
          int slot = kslotb ^ swz7(row);
          gload16(&QKV[(size_t)(nk0 + row) * QKVW + kbase + slot * 8], Kn + c * 1024);
        }
        va = *(const bf16x8*)&QKV[(size_t)(nk0 + vkv) * QKVW + vbase + vd8];
        vb = *(const bf16x8*)&QKV[(size_t)(nk0 + vkv + 1) * QKVW + vbase + vd8];
        anext = am[nk0 + lane];
      }

      if (valid) {
        // ---- S^T = K Q^T (32x32x16) ----
        f32x16 s0, s1;
#pragma unroll
        for (int i = 0; i < 16; ++i) { s0[i] = 0.f; s1[i] = 0.f; }
        __builtin_amdgcn_s_setprio(1);
#pragma unroll
        for (int ds = 0; ds < 4; ++ds) {
          int off = ds * 32 + hi * 16;
          bf16x8 k0 = *(bf16x8*)&Kc[(col * 128 + off) ^ (swz7(col) << 4)];
          bf16x8 k1 = *(bf16x8*)&Kc[((32 + col) * 128 + off) ^ (swz7(32 + col) << 4)];
          s0 = __builtin_amdgcn_mfma_f32_32x32x16_bf16(k0, qf[ds], s0, 0, 0, 0);
          s1 = __builtin_amdgcn_mfma_f32_32x32x16_bf16(k1, qf[ds], s1, 0, 0, 0);
        }
        __builtin_amdgcn_s_setprio(0);

        // ---- mask (raw domain; CF folded into exp's fma) ----
        float pvv[32];
        unsigned long long m64 = __ballot(acur != 0);
        bool interior = (kv0 + 64 <= qt * 32) && (m64 == ~0ull);
        if (interior) {
#pragma unroll
          for (int r = 0; r < 16; ++r) { pvv[r] = s0[r]; pvv[16 + r] = s1[r]; }
        } else {
#pragma unroll
          for (int b = 0; b < 2; ++b)
#pragma unroll
            for (int r = 0; r < 16; ++r) {
              int kvl = b * 32 + (r & 3) + 8 * (r >> 2) + 4 * hi;
              float sv = b ? s1[r] : s0[r];
              bool ok = (kvl + kv0 <= qrow) && ((m64 >> kvl) & 1ull);
              pvv[b * 16 + r] = ok ? sv : -INFINITY;
            }
        }

        // ---- online softmax (4-way trees + 1 cross-half shfl) ----
        float a0 = pvv[0], a1 = pvv[1], a2 = pvv[2], a3 = pvv[3];
#pragma unroll
        for (int i = 4; i < 32; i += 4) {
          a0 = fmaxf(a0, pvv[i]);     a1 = fmaxf(a1, pvv[i + 1]);
          a2 = fmaxf(a2, pvv[i + 2]); a3 = fmaxf(a3, pvv[i + 3]);
        }
        float lmax = fmaxf(fmaxf(a0, a1), fmaxf(a2, a3));
        lmax = fmaxf(lmax, __shfl_xor(lmax, 32));
        float lmaxs = lmax * CF;

        if (!__all(lmaxs - m_i <= 8.f)) {   // defer-max (T13)
          float nm = fmaxf(m_i, lmaxs);
          float al = __builtin_amdgcn_exp2f(m_i - nm);
          m_i = nm;
          l_part *= al;
#pragma unroll
          for (int b = 0; b < 2; ++b)
#pragma unroll
            for (int i = 0; i < 16; ++i) Oacc[b][i] *= al;
        }

        float t0 = 0.f, t1 = 0.f, t2 = 0.f, t3 = 0.f;
#pragma unroll
        for (int i = 0; i < 32; i += 4) {
          pvv[i]     = __builtin_amdgcn_exp2f(__builtin_fmaf(pvv[i],     CF, -m_i)); t0 += pvv[i];
          pvv[i + 1] = __builtin_amdgcn_exp2f(__builtin_fmaf(pvv[i + 1], CF, -m_i)); t1 += pvv[i + 1];
          pvv[i + 2] = __builtin_amdgcn_exp2f(__builtin_fmaf(pvv[i + 2], CF, -m_i)); t2 += pvv[i + 2];
          pvv[i + 3] = __builtin_amdgcn_exp2f(__builtin_fmaf(pvv[i + 3], CF, -m_i)); t3 += pvv[i + 3];
        }
        l_part += (t0 + t1) + (t2 + t3);

        // ---- P -> PV B-fragments in-register via cvt_pk + permlane32_swap ----
        bf16x8 pf[4];
#pragma unroll
        for (int b = 0; b < 2; ++b)
#pragma unroll
          for (int gg = 0; gg < 2; ++gg) {
            int base = b * 16 + gg * 8;
            u32 A1 = cvtpk(pvv[base + 0], pvv[base + 1]);
            u32 A2 = cvtpk(pvv[base + 2], pvv[base + 3]);
            u32 B1 = cvtpk(pvv[base + 4], pvv[base + 5]);
            u32 B2 = cvtpk(pvv[base + 6], pvv[base + 7]);
            pls(A1, B1);
            pls(A2, B2);
            u32x4 pw; pw[0] = A1; pw[1] = A2; pw[2] = B1; pw[3] = B2;
            pf[b * 2 + gg] = *reinterpret_cast<bf16x8*>(&pw);
          }

        // ---- O^T += V^T P^T ----
        __builtin_amdgcn_s_setprio(1);
#pragma unroll
        for (int ks = 0; ks < 4; ++ks) {
          int off = ks * 32 + hi * 16;
#pragma unroll
          for (int db = 0; db < 2; ++db) {
            int d = db * 32 + col;
            bf16x8 vf = *(bf16x8*)&Vc[(d * 128 + off) ^ (swz7(d) << 4)];
            Oacc[db] = __builtin_amdgcn_mfma_f32_32x32x16_bf16(vf, pf[ks], Oacc[db], 0, 0, 0);
          }
        }
        __builtin_amdgcn_s_setprio(0);
      }

      // ---- late half of async stage: pack + write V^T(next) ----
      if (pre) {
#pragma unroll
        for (int i = 0; i < 8; ++i) {
          int d = vd8 + i;
          u32 pk = (u32)(u16)va[i] | ((u32)(u16)vb[i] << 16);
          *(u32*)&Vn[(d * 128 + vkv * 2) ^ (swz7(d) << 4)] = pk;
        }
        acur = anext;
      }
      __syncthreads();
    }

    // ---- 3-way merge: groups 0,1 write stride-33 pools, group 2 merges ----
    float l_p = l_part + __shfl_xor(l_part, 32);

    if (g < 2) {
      // pool_g at smem + g*33792 (overlays staging, dead until next phase)
      float* pool = (float*)(smem + g * 33792) + w * 2112 + lane * 33;
#pragma unroll
      for (int b = 0; b < 2; ++b)
#pragma unroll
        for (int i = 0; i < 16; ++i) pool[b * 16 + i] = Oacc[b][i];
      mlb[g][w][lane] = make_float2(m_i, l_p);
    }
    __syncthreads();
    if (g == 2) {
      const float* p0 = (float*)(smem + 0)     + w * 2112 + lane * 33;
      const float* p1 = (float*)(smem + 33792) + w * 2112 + lane * 33;
      float2 ml0 = mlb[0][w][lane];
      float2 ml1 = mlb[1][w][lane];
      float mm = fmaxf(fmaxf(ml0.x, ml1.x), m_i);
      float b0 = __builtin_amdgcn_exp2f(ml0.x - mm);
      float b1 = __builtin_amdgcn_exp2f(ml1.x - mm);
      float b2 = __builtin_amdgcn_exp2f(m_i - mm);
      float linv = 1.0f / (ml0.y * b0 + ml1.y * b1 + l_p * b2);
      b0 *= linv; b1 *= linv; b2 *= linv;
#pragma unroll
      for (int db = 0; db < 2; ++db)
#pragma unroll
        for (int qd = 0; qd < 4; ++qd) {
          float o0 = p0[db * 16 + qd * 4 + 0] * b0 + p1[db * 16 + qd * 4 + 0] * b1 + Oacc[db][qd * 4 + 0] * b2;
          float o1 = p0[db * 16 + qd * 4 + 1] * b0 + p1[db * 16 + qd * 4 + 1] * b1 + Oacc[db][qd * 4 + 1] * b2;
          float o2 = p0[db * 16 + qd * 4 + 2] * b0 + p1[db * 16 + qd * 4 + 2] * b1 + Oacc[db][qd * 4 + 2] * b2;
          float o3 = p0[db * 16 + qd * 4 + 3] * b0 + p1[db * 16 + qd * 4 + 3] * b1 + Oacc[db][qd * 4 + 3] * b2;
          u32x2 o;
          o[0] = cvtpk(o0, o1);
          o[1] = cvtpk(o2, o3);
          int d0 = db * 32 + qd * 8 + hi * 4;
          *(u32x2*)&Ob[(size_t)qrow * HIDN + h * 64 + d0] = o;
        }
    }
    __syncthreads();  // pools/mlb consumed before next phase's staging
  }
}

extern "C" void kernel_launch(void* const* d_in, const int* in_sizes, int n_in,
                              void* d_out, int out_size, void* d_ws, size_t ws_size,
                              hipStream_t stream) {
  const float* hidden = (const float*)d_in[0];
  const int*   am     = (const int*)d_in[1];
  const float* Wq     = (const float*)d_in[2];
  const float* Wk     = (const float*)d_in[3];
  const float* Wv     = (const float*)d_in[4];
  const float* Wo     = (const float*)d_in[5];
  float* out = (float*)d_out;

  s16* hb    = (s16*)d_ws;          // hidden  [2048][2048]
  s16* wqkvb = hb    + 4194304;     // W_qkv   [3072][2048]
  s16* wob   = wqkvb + 6291456;     // Wo      [2048][2048]
  s16* QKVb  = wob   + 4194304;     // QKV     [2048][3072]
  s16* Ab    = QKVb  + 6291456;     // attnout [2048][2048]

  cvt_all<<<14336, 256, 0, stream>>>(hidden, Wq, Wk, Wv, Wo, (s16x4*)d_ws);

  gemm_bt<s16><<<384, 512, 0, stream>>>(hb, wqkvb, QKVb, 2048, 3072, 2048, 24);

  attn_kernel<<<dim3(8, 32), 768, 0, stream>>>(QKVb, am, Ab);

  gemm_bt<float><<<256, 512, 0, stream>>>(Ab, wob, out, 2048, 2048, 2048, 16);
}

// Round 20
// 131.272 us; speedup vs baseline: 1.2191x; 1.2191x over previous
//
#include <hip/hip_runtime.h>
#include <hip/hip_bf16.h>
#include <math.h>

typedef __attribute__((ext_vector_type(4))) float f32x4;
typedef __attribute__((ext_vector_type(16))) float f32x16;
typedef __attribute__((ext_vector_type(8))) short bf16x8;
typedef __attribute__((ext_vector_type(4))) short s16x4;
typedef __attribute__((ext_vector_type(4))) unsigned int u32x4;
typedef __attribute__((ext_vector_type(2))) unsigned int u32x2;
typedef short s16;
typedef unsigned int u32;
typedef unsigned short u16;

#define S_LEN 2048
#define HIDN  2048
#define QKVW  3072
#define NH    32
#define NKVH  8
#define HD    64

__device__ __forceinline__ s16 f2bf(float f) {
  unsigned int u = __float_as_uint(f);
  unsigned int lsb = (u >> 16) & 1u;
  u += 0x7fffu + lsb;
  return (s16)(u >> 16);
}

__device__ __forceinline__ u32 cvtpk(float lo, float hi) {
  u32 r;
  asm("v_cvt_pk_bf16_f32 %0, %1, %2" : "=v"(r) : "v"(lo), "v"(hi));
  return r;
}

__device__ __forceinline__ void gload16(const void* g, void* l) {
  __builtin_amdgcn_global_load_lds(
      (const __attribute__((address_space(1))) void*)g,
      (__attribute__((address_space(3))) void*)l, 16, 0, 0);
}

// v_permlane32_swap_b32: a.hi-lanes <-> b.lo-lanes
__device__ __forceinline__ void pls(u32& a, u32& b) {
  asm volatile("v_permlane32_swap_b32 %0, %1" : "+v"(a), "+v"(b));
}

__device__ __forceinline__ int swz7(int row) { return (row ^ (row >> 3)) & 7; }

// all 5 f32->bf16 conversions in one launch; dest regions are contiguous in ws
__global__ __launch_bounds__(256) void cvt_all(const float* __restrict__ h,
                                               const float* __restrict__ wq,
                                               const float* __restrict__ wk,
                                               const float* __restrict__ wv,
                                               const float* __restrict__ wo,
                                               s16x4* __restrict__ dst) {
  int i = blockIdx.x * 256 + threadIdx.x;
  const float* src; int off;
  if (i < 1048576)      { src = h;  off = i; }
  else if (i < 2097152) { src = wq; off = i - 1048576; }
  else if (i < 2359296) { src = wk; off = i - 2097152; }
  else if (i < 2621440) { src = wv; off = i - 2359296; }
  else                  { src = wo; off = i - 2621440; }
  if (i < 3670016) {
    float4 f = reinterpret_cast<const float4*>(src)[off];
    s16x4 o;
    o.x = f2bf(f.x); o.y = f2bf(f.y); o.z = f2bf(f.z); o.w = f2bf(f.w);
    dst[i] = o;
  }
}

__device__ __forceinline__ void storeC(s16* C, size_t idx, float v)   { C[idx] = f2bf(v); }
__device__ __forceinline__ void storeC(float* C, size_t idx, float v) { C[idx] = v; }

// C[M,N] = A[M,K] * B[N,K]^T. BM=BN=128, BK=64, 512 threads (8 waves 2x4),
// double-buffered LDS, 2-phase schedule, swz7 slot swizzle, XCD block swizzle.
template <typename OUT_T>
__global__ __launch_bounds__(512) void gemm_bt(const s16* __restrict__ A,
                                               const s16* __restrict__ B,
                                               OUT_T* __restrict__ C,
                                               int M, int N, int K, int gridX) {
  __shared__ alignas(16) s16 As[2][8192];   // [128][64], 16KB each
  __shared__ alignas(16) s16 Bs[2][8192];

  // bijective XCD swizzle (m204): each XCD gets a contiguous tile range
  const int nwg  = (M >> 7) * gridX;
  const int flat = blockIdx.x;
  const int q8   = nwg >> 3;
  const int swz  = (flat & 7) * q8 + (flat >> 3);
  const int bm   = (swz / gridX) * 128;
  const int bn   = (swz % gridX) * 128;

  const int t    = threadIdx.x;
  const int lane = t & 63;
  const int w    = t >> 6;            // 0..7
  const int wr   = (w >> 2) * 64;     // wave-tile 64x32
  const int wc   = (w & 3) * 32;
  const int lr   = lane & 15;
  const int lg   = lane >> 4;

  // staging: 16 chunks of 1KB per matrix; wave w does chunks {2w, 2w+1}
  const int srow0 = (w * 2) * 8 + (lane >> 3);
  const int srow1 = (w * 2 + 1) * 8 + (lane >> 3);
  const int sl0   = ((lane & 7) ^ swz7(srow0)) * 8;
  const int sl1   = ((lane & 7) ^ swz7(srow1)) * 8;

  f32x4 acc[4][2];
#pragma unroll
  for (int m = 0; m < 4; ++m)
#pragma unroll
    for (int n = 0; n < 2; ++n)
      acc[m][n] = (f32x4){0.f, 0.f, 0.f, 0.f};

  const int nK = K >> 6;
  int buf = 0;

  // prologue: stage tile 0
  {
    gload16(&A[(size_t)(bm + srow0) * K + sl0], (char*)As[0] + (w * 2) * 1024);
    gload16(&A[(size_t)(bm + srow1) * K + sl1], (char*)As[0] + (w * 2 + 1) * 1024);
    gload16(&B[(size_t)(bn + srow0) * K + sl0], (char*)Bs[0] + (w * 2) * 1024);
    gload16(&B[(size_t)(bn + srow1) * K + sl1], (char*)Bs[0] + (w * 2 + 1) * 1024);
  }
  __syncthreads();

  for (int ki = 0; ki < nK; ++ki) {
    if (ki + 1 < nK) {
      const int kt = (ki + 1) << 6;
      gload16(&A[(size_t)(bm + srow0) * K + kt + sl0], (char*)As[buf ^ 1] + (w * 2) * 1024);
      gload16(&A[(size_t)(bm + srow1) * K + kt + sl1], (char*)As[buf ^ 1] + (w * 2 + 1) * 1024);
      gload16(&B[(size_t)(bn + srow0) * K + kt + sl0], (char*)Bs[buf ^ 1] + (w * 2) * 1024);
      gload16(&B[(size_t)(bn + srow1) * K + kt + sl1], (char*)Bs[buf ^ 1] + (w * 2 + 1) * 1024);
    }

    bf16x8 af[4][2], bfr[2][2];
#pragma unroll
    for (int kk = 0; kk < 2; ++kk) {
#pragma unroll
      for (int m = 0; m < 4; ++m) {
        int row = wr + m * 16 + lr;
        af[m][kk] = *(bf16x8*)((char*)As[buf] + row * 128 + (((kk * 4 + lg) ^ swz7(row)) << 4));
      }
#pragma unroll
      for (int n = 0; n < 2; ++n) {
        int row = wc + n * 16 + lr;
        bfr[n][kk] = *(bf16x8*)((char*)Bs[buf] + row * 128 + (((kk * 4 + lg) ^ swz7(row)) << 4));
      }
    }

    __builtin_amdgcn_s_setprio(1);
#pragma unroll
    for (int m = 0; m < 4; ++m)
#pragma unroll
      for (int n = 0; n < 2; ++n)
#pragma unroll
        for (int kk = 0; kk < 2; ++kk)
          acc[m][n] = __builtin_amdgcn_mfma_f32_16x16x32_bf16(af[m][kk], bfr[n][kk], acc[m][n], 0, 0, 0);
    __builtin_amdgcn_s_setprio(0);

    __syncthreads();
    buf ^= 1;
  }

#pragma unroll
  for (int m = 0; m < 4; ++m)
#pragma unroll
    for (int n = 0; n < 2; ++n) {
      int row = bm + wr + m * 16 + lg * 4;
      int col = bn + wc + n * 16 + lr;
#pragma unroll
      for (int j = 0; j < 4; ++j)
        storeC(C, (size_t)(row + j) * N + col, acc[m][n][j]);
    }
}

// ---------------- flash attention: split-KV 8-wave, uniform paired blocks ----
// Block = (hk, p): phase 0 runs q-tile 63-p, phase 1 runs q-tile p (uniform
// 16-17 rounds/block). 512 threads = 2 KV-split groups x 4 heads; group g owns
// KV tiles 2i+g with private double-buffered K/V LDS; in-LDS merge per phase.
// Merge pool uses 33-float lane stride (bank = lane, conflict-free).
__global__ __launch_bounds__(512) void attn_kernel(
    const s16* __restrict__ QKV,   // [2048][3072]
    const int* __restrict__ am,    // [2048]
    s16* __restrict__ Ob) {        // [2048][2048]
  // [group][buf]: K at +0 (8KB), V^T at +8192 (8KB); 64KB total.
  __shared__ alignas(16) char smem[65536];
  __shared__ float2 mlb[4][64];

  const int t    = threadIdx.x;
  const int g    = t >> 8;        // kv-split group
  const int tg   = t & 255;       // tid within group
  const int lane = t & 63;
  const int w    = tg >> 6;       // head index within group
  const int col  = lane & 31;     // q column (this wave's q-row index)
  const int hi   = lane >> 5;

  const int hk = blockIdx.x;
  const int p  = blockIdx.y;      // 0..31
  const int h  = hk * 4 + w;
  const int kbase = 2048 + hk * 64;
  const int vbase = 2560 + hk * 64;
  const float CF = 0.18033688f;  // 0.125 * log2(e)

  const int krow   = lane >> 3;
  const int kslotb = lane & 7;
  const int vkv    = 2 * (tg >> 3);
  const int vd8    = (tg & 7) * 8;

  for (int phase = 0; phase < 2; ++phase) {
    const int qt = phase ? p : 63 - p;
    const int nt = (qt >> 1) + 1;
    const int R  = (nt + 1) >> 1;   // rounds (2 tiles per round)
    const int qrow = qt * 32 + col;

    bf16x8 qf[4];
#pragma unroll
    for (int ds = 0; ds < 4; ++ds)
      qf[ds] = *(const bf16x8*)&QKV[(size_t)qrow * QKVW + h * 64 + ds * 16 + hi * 8];

    // ---- prologue: group g stages tile g into its buf 0 ----
    if (g < nt) {
      char* Kn = smem + (g * 2 + 0) * 16384;
      char* Vn = Kn + 8192;
#pragma unroll
      for (int pp = 0; pp < 2; ++pp) {
        int c   = w * 2 + pp;
        int row = c * 8 + krow;
        int slot = kslotb ^ swz7(row);
        gload16(&QKV[(size_t)(g * 64 + row) * QKVW + kbase + slot * 8], Kn + c * 1024);
      }
      bf16x8 va = *(const bf16x8*)&QKV[(size_t)(g * 64 + vkv) * QKVW + vbase + vd8];
      bf16x8 vb = *(const bf16x8*)&QKV[(size_t)(g * 64 + vkv + 1) * QKVW + vbase + vd8];
#pragma unroll
      for (int i = 0; i < 8; ++i) {
        int d = vd8 + i;
        u32 pk = (u32)(u16)va[i] | ((u32)(u16)vb[i] << 16);
        *(u32*)&Vn[(d * 128 + vkv * 2) ^ (swz7(d) << 4)] = pk;
      }
    }
    int acur = am[g * 64 + lane];

    float m_i = -1e30f, l_part = 0.f;
    f32x16 Oacc[2];
#pragma unroll
    for (int b = 0; b < 2; ++b)
#pragma unroll
      for (int i = 0; i < 16; ++i) Oacc[b][i] = 0.f;
    __syncthreads();

    for (int it = 0; it < R; ++it) {
      const int buf  = it & 1;
      const int tile = 2 * it + g;
      const bool valid = (tile < nt);
      const int kv0  = tile * 64;
      const bool pre = (tile + 2 < nt);

      char* Kc = smem + (g * 2 + buf) * 16384;
      char* Vc = Kc + 8192;
      char* Kn = smem + (g * 2 + (buf ^ 1)) * 16384;
      char* Vn = Kn + 8192;

      // ---- async stage of this group's next tile (issue early) ----
      bf16x8 va, vb;
      int anext = 0;
      if (pre) {
        const int nk0 = kv0 + 128;
#pragma unroll
        for (int pp = 0; pp < 2; ++pp) {
          int c   = w * 2 + pp;
          int row = c * 8 + krow;
          int slot = kslotb ^ swz7(row);
          gload16(&QKV[(size_t)(nk0 + row) * QKVW + kbase + slot * 8], Kn + c * 1024);
        }
        va = *(const bf16x8*)&QKV[(size_t)(nk0 + vkv) * QKVW + vbase + vd8];
        vb = *(const bf16x8*)&QKV[(size_t)(nk0 + vkv + 1) * QKVW + vbase + vd8];
        anext = am[nk0 + lane];
      }

      if (valid) {
        // ---- S^T = K Q^T (32x32x16) ----
        f32x16 s0, s1;
#pragma unroll
        for (int i = 0; i < 16; ++i) { s0[i] = 0.f; s1[i] = 0.f; }
        __builtin_amdgcn_s_setprio(1);
#pragma unroll
        for (int ds = 0; ds < 4; ++ds) {
          int off = ds * 32 + hi * 16;
          bf16x8 k0 = *(bf16x8*)&Kc[(col * 128 + off) ^ (swz7(col) << 4)];
          bf16x8 k1 = *(bf16x8*)&Kc[((32 + col) * 128 + off) ^ (swz7(32 + col) << 4)];
          s0 = __builtin_amdgcn_mfma_f32_32x32x16_bf16(k0, qf[ds], s0, 0, 0, 0);
          s1 = __builtin_amdgcn_mfma_f32_32x32x16_bf16(k1, qf[ds], s1, 0, 0, 0);
        }
        __builtin_amdgcn_s_setprio(0);

        // ---- mask (raw domain; CF folded into exp's fma) ----
        float pvv[32];
        unsigned long long m64 = __ballot(acur != 0);
        bool interior = (kv0 + 64 <= qt * 32) && (m64 == ~0ull);
        if (interior) {
#pragma unroll
          for (int r = 0; r < 16; ++r) { pvv[r] = s0[r]; pvv[16 + r] = s1[r]; }
        } else {
#pragma unroll
          for (int b = 0; b < 2; ++b)
#pragma unroll
            for (int r = 0; r < 16; ++r) {
              int kvl = b * 32 + (r & 3) + 8 * (r >> 2) + 4 * hi;
              float sv = b ? s1[r] : s0[r];
              bool ok = (kvl + kv0 <= qrow) && ((m64 >> kvl) & 1ull);
              pvv[b * 16 + r] = ok ? sv : -INFINITY;
            }
        }

        // ---- online softmax (4-way trees + 1 cross-half shfl) ----
        float a0 = pvv[0], a1 = pvv[1], a2 = pvv[2], a3 = pvv[3];
#pragma unroll
        for (int i = 4; i < 32; i += 4) {
          a0 = fmaxf(a0, pvv[i]);     a1 = fmaxf(a1, pvv[i + 1]);
          a2 = fmaxf(a2, pvv[i + 2]); a3 = fmaxf(a3, pvv[i + 3]);
        }
        float lmax = fmaxf(fmaxf(a0, a1), fmaxf(a2, a3));
        lmax = fmaxf(lmax, __shfl_xor(lmax, 32));
        float lmaxs = lmax * CF;

        if (!__all(lmaxs - m_i <= 8.f)) {   // defer-max (T13)
          float nm = fmaxf(m_i, lmaxs);
          float al = __builtin_amdgcn_exp2f(m_i - nm);
          m_i = nm;
          l_part *= al;
#pragma unroll
          for (int b = 0; b < 2; ++b)
#pragma unroll
            for (int i = 0; i < 16; ++i) Oacc[b][i] *= al;
        }

        float t0 = 0.f, t1 = 0.f, t2 = 0.f, t3 = 0.f;
#pragma unroll
        for (int i = 0; i < 32; i += 4) {
          pvv[i]     = __builtin_amdgcn_exp2f(__builtin_fmaf(pvv[i],     CF, -m_i)); t0 += pvv[i];
          pvv[i + 1] = __builtin_amdgcn_exp2f(__builtin_fmaf(pvv[i + 1], CF, -m_i)); t1 += pvv[i + 1];
          pvv[i + 2] = __builtin_amdgcn_exp2f(__builtin_fmaf(pvv[i + 2], CF, -m_i)); t2 += pvv[i + 2];
          pvv[i + 3] = __builtin_amdgcn_exp2f(__builtin_fmaf(pvv[i + 3], CF, -m_i)); t3 += pvv[i + 3];
        }
        l_part += (t0 + t1) + (t2 + t3);

        // ---- P -> PV B-fragments in-register via cvt_pk + permlane32_swap ----
        bf16x8 pf[4];
#pragma unroll
        for (int b = 0; b < 2; ++b)
#pragma unroll
          for (int gg = 0; gg < 2; ++gg) {
            int base = b * 16 + gg * 8;
            u32 A1 = cvtpk(pvv[base + 0], pvv[base + 1]);
            u32 A2 = cvtpk(pvv[base + 2], pvv[base + 3]);
            u32 B1 = cvtpk(pvv[base + 4], pvv[base + 5]);
            u32 B2 = cvtpk(pvv[base + 6], pvv[base + 7]);
            pls(A1, B1);
            pls(A2, B2);
            u32x4 pw; pw[0] = A1; pw[1] = A2; pw[2] = B1; pw[3] = B2;
            pf[b * 2 + gg] = *reinterpret_cast<bf16x8*>(&pw);
          }

        // ---- O^T += V^T P^T ----
        __builtin_amdgcn_s_setprio(1);
#pragma unroll
        for (int ks = 0; ks < 4; ++ks) {
          int off = ks * 32 + hi * 16;
#pragma unroll
          for (int db = 0; db < 2; ++db) {
            int d = db * 32 + col;
            bf16x8 vf = *(bf16x8*)&Vc[(d * 128 + off) ^ (swz7(d) << 4)];
            Oacc[db] = __builtin_amdgcn_mfma_f32_32x32x16_bf16(vf, pf[ks], Oacc[db], 0, 0, 0);
          }
        }
        __builtin_amdgcn_s_setprio(0);
      }

      // ---- late half of async stage: pack + write V^T(next) ----
      if (pre) {
#pragma unroll
        for (int i = 0; i < 8; ++i) {
          int d = vd8 + i;
          u32 pk = (u32)(u16)va[i] | ((u32)(u16)vb[i] << 16);
          *(u32*)&Vn[(d * 128 + vkv * 2) ^ (swz7(d) << 4)] = pk;
        }
        acur = anext;
      }
      __syncthreads();
    }

    // ---- merge the two groups' partials (in LDS), g1 stores final O ----
    // pool stride = 33 floats/lane: bank = (lane*33)%32 = lane, conflict-free.
    float l_p = l_part + __shfl_xor(l_part, 32);

    if (g == 0) {
      float* pool = (float*)smem + w * 2176 + lane * 33;
#pragma unroll
      for (int b = 0; b < 2; ++b)
#pragma unroll
        for (int i = 0; i < 16; ++i) pool[b * 16 + i] = Oacc[b][i];
      mlb[w][lane] = make_float2(m_i, l_p);
    }
    __syncthreads();
    if (g == 1) {
      const float* pool = (const float*)smem + w * 2176 + lane * 33;
      float2 ml0 = mlb[w][lane];
      float mm = fmaxf(ml0.x, m_i);
      float b0 = __builtin_amdgcn_exp2f(ml0.x - mm);
      float b1 = __builtin_amdgcn_exp2f(m_i - mm);
      float linv = 1.0f / (ml0.y * b0 + l_p * b1);
      float sc0 = b0 * linv, sc1 = b1 * linv;
#pragma unroll
      for (int db = 0; db < 2; ++db)
#pragma unroll
        for (int qd = 0; qd < 4; ++qd) {
          float o0 = pool[db * 16 + qd * 4 + 0] * sc0 + Oacc[db][qd * 4 + 0] * sc1;
          float o1 = pool[db * 16 + qd * 4 + 1] * sc0 + Oacc[db][qd * 4 + 1] * sc1;
          float o2 = pool[db * 16 + qd * 4 + 2] * sc0 + Oacc[db][qd * 4 + 2] * sc1;
          float o3 = pool[db * 16 + qd * 4 + 3] * sc0 + Oacc[db][qd * 4 + 3] * sc1;
          u32x2 o;
          o[0] = cvtpk(o0, o1);
          o[1] = cvtpk(o2, o3);
          int d0 = db * 32 + qd * 8 + hi * 4;
          *(u32x2*)&Ob[(size_t)qrow * HIDN + h * 64 + d0] = o;
        }
    }
    __syncthreads();  // pool/mlb consumed before next phase's staging
  }
}

extern "C" void kernel_launch(void* const* d_in, const int* in_sizes, int n_in,
                              void* d_out, int out_size, void* d_ws, size_t ws_size,
                              hipStream_t stream) {
  const float* hidden = (const float*)d_in[0];
  const int*   am     = (const int*)d_in[1];
  const float* Wq     = (const float*)d_in[2];
  const float* Wk     = (const float*)d_in[3];
  const float* Wv     = (const float*)d_in[4];
  const float* Wo     = (const float*)d_in[5];
  float* out = (float*)d_out;

  s16* hb    = (s16*)d_ws;          // hidden  [2048][2048]
  s16* wqkvb = hb    + 4194304;     // W_qkv   [3072][2048]
  s16* wob   = wqkvb + 6291456;     // Wo      [2048][2048]
  s16* QKVb  = wob   + 4194304;     // QKV     [2048][3072]
  s16* Ab    = QKVb  + 6291456;     // attnout [2048][2048]

  cvt_all<<<14336, 256, 0, stream>>>(hidden, Wq, Wk, Wv, Wo, (s16x4*)d_ws);

  gemm_bt<s16><<<384, 512, 0, stream>>>(hb, wqkvb, QKVb, 2048, 3072, 2048, 24);

  attn_kernel<<<dim3(8, 32), 512, 0, stream>>>(QKVb, am, Ab);

  gemm_bt<float><<<256, 512, 0, stream>>>(Ab, wob, out, 2048, 2048, 2048, 16);
}